// Round 8
// baseline (1245.385 us; speedup 1.0000x reference)
//
#include <hip/hip_runtime.h>

#define NN 100000
#define NE 3200000
#define NF 128
#define C1 32
#define C2 16
#define NG 64
#define BKT_SH 7
#define BKT_W  128
#define NBKT   782          // ceil(NN/128)
#define CH     8192         // edges per partition chunk
#define NW     391          // ceil(NE/CH)
#define RSTR   784          // runstart row stride (783 used)
#define MAPCAP 6400         // per-bucket flattened-edge capacity (mean 4092, sd 64)

// ---- workspace layout (4-byte element offsets) ----
#define OFF_RUN   0                    // NW*RSTR = 306,544 ints
#define OFF_DIS   306544               // NN floats
#define OFF_POOL  406544               // NG*C2 floats
#define OFF_CNTF  407568               // NG floats
#define OFF_EDG   407632               // NE uints (persists through agg2)
#define OFF_XS1H0 3607632              // NN*8 uints (bf16x2, cols 0..15)
#define OFF_XS1H1 4407632              // NN*8 uints (cols 16..31)
#define OFF_H1H0  5207632              // NN*16 floats (h1 cols 0..15)
#define OFF_XS2B  6807632              // NN*8 uints (bf16x2, 16 cols)

// ---- bf16x2 pack/unpack (RNE) ----
__device__ __forceinline__ unsigned pack_bf2(float a, float b) {
    unsigned ua = __float_as_uint(a);
    unsigned ub = __float_as_uint(b);
    ua = (ua + 0x7fffu + ((ua >> 16) & 1u)) >> 16;
    ub = (ub + 0x7fffu + ((ub >> 16) & 1u)) & 0xffff0000u;
    return ua | ub;   // lo = a, hi = b
}
__device__ __forceinline__ float2 unpack_bf2(unsigned u) {
    return make_float2(__uint_as_float(u << 16), __uint_as_float(u & 0xffff0000u));
}

// ---------------- k_part: per-chunk counting sort by bucket -----------------
__global__ __launch_bounds__(256) void k_part(
    const int* __restrict__ S, const int* __restrict__ D,
    unsigned* __restrict__ edgebuf, int* __restrict__ runstart)
{
    __shared__ int lhist[1024];
    __shared__ int lstart[1024];
    __shared__ int lcur[NBKT];
    __shared__ int sd[256];
    __shared__ unsigned lsort[CH];
    const int w = blockIdx.x;
    const int t = threadIdx.x;
    const int e0 = w * CH;
    const int n = min(CH, NE - e0);

    for (int i = t; i < 1024; i += 256) lhist[i] = 0;
    __syncthreads();
    for (int i = t; i < n; i += 256)
        atomicAdd(&lhist[(unsigned)D[e0 + i] >> BKT_SH], 1);
    __syncthreads();
    int c0 = lhist[t * 4 + 0], c1 = lhist[t * 4 + 1];
    int c2 = lhist[t * 4 + 2], c3 = lhist[t * 4 + 3];
    int ts = c0 + c1 + c2 + c3;
    sd[t] = ts;
    __syncthreads();
    for (int off = 1; off < 256; off <<= 1) {
        int v = (t >= off) ? sd[t - off] : 0;
        __syncthreads();
        sd[t] += v;
        __syncthreads();
    }
    int excl = sd[t] - ts;
    lstart[t * 4 + 0] = excl;
    lstart[t * 4 + 1] = excl + c0;
    lstart[t * 4 + 2] = excl + c0 + c1;
    lstart[t * 4 + 3] = excl + c0 + c1 + c2;
    __syncthreads();
    for (int i = t; i < 783; i += 256) runstart[w * RSTR + i] = lstart[i];
    for (int i = t; i < NBKT; i += 256) lcur[i] = lstart[i];
    __syncthreads();
    for (int i = t; i < n; i += 256) {
        int s = S[e0 + i], d = D[e0 + i];
        int pos = atomicAdd(&lcur[(unsigned)d >> BKT_SH], 1);
        lsort[pos] = ((unsigned)s << BKT_SH) | (unsigned)(d & (BKT_W - 1));
    }
    __syncthreads();
    for (int i = t; i < n; i += 256) edgebuf[e0 + i] = lsort[i];
}

// ---- shared preamble macro: run lengths -> pfx -> basea -> map -> s_total ---
#define BUCKET_PREAMBLE(EXTRA_INIT)                                            \
    const int b = blockIdx.x;                                                  \
    const int t = threadIdx.x;                                                 \
    for (int w = t; w < NW; w += 256) {                                        \
        int s0 = runstart[w * RSTR + b];                                       \
        int s1 = runstart[w * RSTR + b + 1];                                   \
        basea[w] = s0;                                                         \
        rl[w] = s1 - s0;                                                       \
    }                                                                          \
    EXTRA_INIT                                                                 \
    __syncthreads();                                                           \
    {                                                                          \
        int w0 = t * 2;                                                        \
        int c0_ = (w0 < NW) ? rl[w0] : 0;                                      \
        int c1_ = (w0 + 1 < NW) ? rl[w0 + 1] : 0;                              \
        int ts_ = c0_ + c1_;                                                   \
        sd[t] = ts_;                                                           \
        __syncthreads();                                                       \
        for (int off = 1; off < 256; off <<= 1) {                              \
            int v_ = (t >= off) ? sd[t - off] : 0;                             \
            __syncthreads();                                                   \
            sd[t] += v_;                                                       \
            __syncthreads();                                                   \
        }                                                                      \
        int excl_ = sd[t] - ts_;                                               \
        if (w0 < NW)     pfx[w0]     = excl_;                                  \
        if (w0 + 1 < NW) pfx[w0 + 1] = excl_ + c0_;                            \
        if (t == 255) s_total = sd[255];                                       \
    }                                                                          \
    __syncthreads();                                                           \
    for (int w = t; w < NW; w += 256) {                                        \
        int p_ = pfx[w], len_ = rl[w];                                         \
        basea[w] = w * CH + basea[w] - p_;                                     \
        for (int i = 0; i < len_; ++i) map[p_ + i] = (unsigned short)w;        \
    }

// ---------------- k_nodeinfo: per-bucket degree -> dis ----------------
__global__ __launch_bounds__(256) void k_nodeinfo(
    const unsigned* __restrict__ edgebuf, const int* __restrict__ runstart,
    float* __restrict__ dis)
{
    __shared__ int rl[NW], pfx[NW], basea[NW];
    __shared__ unsigned short map[MAPCAP];
    __shared__ int lcnt[BKT_W];
    __shared__ int sd[256];
    __shared__ int s_total;
    BUCKET_PREAMBLE(if (t < BKT_W) lcnt[t] = 0;)
    __syncthreads();
    const int total = s_total;
    for (int j = t; j < total; j += 256) {
        unsigned p = edgebuf[basea[map[j]] + j];
        atomicAdd(&lcnt[p & (BKT_W - 1)], 1);
    }
    __syncthreads();
    if (t < BKT_W) {
        int node = b * BKT_W + t;
        if (node < NN) dis[node] = rsqrtf((float)lcnt[t] + 1.0f);
    }
}

// ---------------- GEMM1: xs1h{0,1} = bf16x2{(x @ W1) * dis} -----------------
__global__ __launch_bounds__(256) void k_gemm1(
    const float* __restrict__ x, const float* __restrict__ W1,
    const float* __restrict__ dis,
    unsigned* __restrict__ xs1h0, unsigned* __restrict__ xs1h1)
{
    __shared__ float xls[128 * 33];
    __shared__ float wls[32 * 32];
    const int t = threadIdx.x;
    const int tc = t & 7;
    const int tr = t >> 3;
    const int base = blockIdx.x * 128;

    float a[4][4] = {};

    for (int k0 = 0; k0 < NF; k0 += 32) {
        {
            int i = t * 4;
            int kk = i >> 5, c = i & 31;
            *(float4*)&wls[kk * 32 + c] = *(const float4*)&W1[(k0 + kk) * C1 + c];
        }
        #pragma unroll
        for (int r = 0; r < 4; ++r) {
            int n = (t >> 3) + r * 32;
            int j = (t & 7) * 4;
            int node = base + n;
            float4 v = make_float4(0.f, 0.f, 0.f, 0.f);
            if (node < NN) v = *(const float4*)&x[(long long)node * NF + k0 + j];
            xls[n * 33 + j + 0] = v.x;
            xls[n * 33 + j + 1] = v.y;
            xls[n * 33 + j + 2] = v.z;
            xls[n * 33 + j + 3] = v.w;
        }
        __syncthreads();
        #pragma unroll 8
        for (int kk = 0; kk < 32; ++kk) {
            float4 w = *(const float4*)&wls[kk * 32 + tc * 4];
            #pragma unroll
            for (int i = 0; i < 4; ++i) {
                float xv = xls[(tr * 4 + i) * 33 + kk];
                a[i][0] = fmaf(xv, w.x, a[i][0]);
                a[i][1] = fmaf(xv, w.y, a[i][1]);
                a[i][2] = fmaf(xv, w.z, a[i][2]);
                a[i][3] = fmaf(xv, w.w, a[i][3]);
            }
        }
        __syncthreads();
    }
    #pragma unroll
    for (int i = 0; i < 4; ++i) {
        int node = base + tr * 4 + i;
        if (node < NN) {
            float dv = dis[node];
            uint2 o;
            o.x = pack_bf2(a[i][0] * dv, a[i][1] * dv);
            o.y = pack_bf2(a[i][2] * dv, a[i][3] * dv);
            unsigned* dst = (tc < 4) ? &xs1h0[node * 8 + tc * 2]
                                     : &xs1h1[node * 8 + (tc - 4) * 2];
            *(uint2*)dst = o;
        }
    }
}

// ---------------- agg1<HALF>: bucket-LDS aggregation of xs1 half ------------
// HALF 0: writes h1 cols 0..15 (fp32). HALF 1: computes h1 cols 16..31 in LDS,
// reads h1h0 back, fuses GEMM2 epilogue -> xs2b.
template<int HALF>
__global__ __launch_bounds__(256) void k_agg1(
    const unsigned* __restrict__ edgebuf, const int* __restrict__ runstart,
    const unsigned* __restrict__ xsh, const float* __restrict__ dis,
    const float* __restrict__ b1, float* __restrict__ h1h0,
    const float* __restrict__ W2, unsigned* __restrict__ xs2b)
{
    __shared__ int rl[NW], pfx[NW], basea[NW];
    __shared__ unsigned short map[MAPCAP];
    __shared__ float acc[BKT_W * 16];
    __shared__ int sd[256];
    __shared__ int s_total;
    __shared__ float w2s[C1 * C2];
    BUCKET_PREAMBLE(if (HALF == 1 && t < 128) *(float4*)&w2s[t * 4] = *(const float4*)&W2[t * 4];)
    // acc init = self-loop row
    {
        int dl = t >> 1, g8 = t & 1;
        int node = b * BKT_W + dl;
        float* a = &acc[dl * 16 + g8 * 8];
        if (node < NN) {
            uint4 u = *(const uint4*)&xsh[node * 8 + g8 * 4];
            float2 f0 = unpack_bf2(u.x), f1 = unpack_bf2(u.y);
            float2 f2 = unpack_bf2(u.z), f3 = unpack_bf2(u.w);
            a[0] = f0.x; a[1] = f0.y; a[2] = f1.x; a[3] = f1.y;
            a[4] = f2.x; a[5] = f2.y; a[6] = f3.x; a[7] = f3.y;
        } else {
            #pragma unroll
            for (int i = 0; i < 8; ++i) a[i] = 0.f;
        }
    }
    __syncthreads();
    const int total = s_total;
    const int l8 = t & 7;
    for (int j = t >> 3; j < total; j += 32) {
        unsigned p = edgebuf[basea[map[j]] + j];
        int src = (int)(p >> BKT_SH);
        int dl = p & (BKT_W - 1);
        float2 f = unpack_bf2(xsh[src * 8 + l8]);
        atomicAdd(&acc[dl * 16 + l8 * 2], f.x);
        atomicAdd(&acc[dl * 16 + l8 * 2 + 1], f.y);
    }
    __syncthreads();
    // epilogue
    {
        int dl = t >> 1, g8 = t & 1;
        int node = b * BKT_W + dl;
        if (node < NN) {
            float dv = dis[node];
            if (HALF == 0) {
                float o[8];
                #pragma unroll
                for (int c = 0; c < 8; ++c)
                    o[c] = fmaxf(fmaf(acc[dl * 16 + g8 * 8 + c], dv, b1[g8 * 8 + c]), 0.f);
                *(float4*)&h1h0[node * 16 + g8 * 8]     = make_float4(o[0], o[1], o[2], o[3]);
                *(float4*)&h1h0[node * 16 + g8 * 8 + 4] = make_float4(o[4], o[5], o[6], o[7]);
            } else {
                float h[32];
                float4 u0 = *(const float4*)&h1h0[node * 16 + 0];
                float4 u1 = *(const float4*)&h1h0[node * 16 + 4];
                float4 u2 = *(const float4*)&h1h0[node * 16 + 8];
                float4 u3 = *(const float4*)&h1h0[node * 16 + 12];
                h[0] = u0.x; h[1] = u0.y; h[2]  = u0.z; h[3]  = u0.w;
                h[4] = u1.x; h[5] = u1.y; h[6]  = u1.z; h[7]  = u1.w;
                h[8] = u2.x; h[9] = u2.y; h[10] = u2.z; h[11] = u2.w;
                h[12] = u3.x; h[13] = u3.y; h[14] = u3.z; h[15] = u3.w;
                #pragma unroll
                for (int c = 0; c < 16; ++c)
                    h[16 + c] = fmaxf(fmaf(acc[dl * 16 + c], dv, b1[16 + c]), 0.f);
                uint4 ov;
                unsigned o[4];
                #pragma unroll
                for (int cc = 0; cc < 4; ++cc) {
                    int c0 = g8 * 8 + cc * 2;
                    float s0 = 0.f, s1 = 0.f;
                    #pragma unroll
                    for (int k = 0; k < 32; ++k) {
                        s0 = fmaf(h[k], w2s[k * C2 + c0], s0);
                        s1 = fmaf(h[k], w2s[k * C2 + c0 + 1], s1);
                    }
                    o[cc] = pack_bf2(s0 * dv, s1 * dv);
                }
                ov.x = o[0]; ov.y = o[1]; ov.z = o[2]; ov.w = o[3];
                *(uint4*)&xs2b[node * 8 + g8 * 4] = ov;
            }
        }
    }
}

// ---------------- agg2: bucket-LDS aggregation of xs2 + fused pool ----------
__global__ __launch_bounds__(256) void k_agg2(
    const unsigned* __restrict__ edgebuf, const int* __restrict__ runstart,
    const unsigned* __restrict__ xs2b, const float* __restrict__ dis,
    const float* __restrict__ b2, const int* __restrict__ batch,
    float* __restrict__ pool, float* __restrict__ cntf)
{
    __shared__ int rl[NW], pfx[NW], basea[NW];
    __shared__ unsigned short map[MAPCAP];
    __shared__ float acc[BKT_W * 16];
    __shared__ float psum[NG * C2];
    __shared__ float cs[NG];
    __shared__ int sd[256];
    __shared__ int s_total;
    BUCKET_PREAMBLE(
        for (int i = t; i < NG * C2; i += 256) psum[i] = 0.f;
        if (t < NG) cs[t] = 0.f;
    )
    {
        int dl = t >> 1, g8 = t & 1;
        int node = b * BKT_W + dl;
        float* a = &acc[dl * 16 + g8 * 8];
        if (node < NN) {
            uint4 u = *(const uint4*)&xs2b[node * 8 + g8 * 4];
            float2 f0 = unpack_bf2(u.x), f1 = unpack_bf2(u.y);
            float2 f2 = unpack_bf2(u.z), f3 = unpack_bf2(u.w);
            a[0] = f0.x; a[1] = f0.y; a[2] = f1.x; a[3] = f1.y;
            a[4] = f2.x; a[5] = f2.y; a[6] = f3.x; a[7] = f3.y;
        } else {
            #pragma unroll
            for (int i = 0; i < 8; ++i) a[i] = 0.f;
        }
    }
    __syncthreads();
    const int total = s_total;
    const int l8 = t & 7;
    for (int j = t >> 3; j < total; j += 32) {
        unsigned p = edgebuf[basea[map[j]] + j];
        int src = (int)(p >> BKT_SH);
        int dl = p & (BKT_W - 1);
        float2 f = unpack_bf2(xs2b[src * 8 + l8]);
        atomicAdd(&acc[dl * 16 + l8 * 2], f.x);
        atomicAdd(&acc[dl * 16 + l8 * 2 + 1], f.y);
    }
    __syncthreads();
    {
        int dl = t >> 1, g8 = t & 1;
        int node = b * BKT_W + dl;
        if (node < NN) {
            float dv = dis[node];
            int g = batch[node];
            #pragma unroll
            for (int c = 0; c < 8; ++c) {
                float v = fmaf(acc[dl * 16 + g8 * 8 + c], dv, b2[g8 * 8 + c]);
                atomicAdd(&psum[g * C2 + g8 * 8 + c], v);
            }
            if (g8 == 0) atomicAdd(&cs[g], 1.0f);
        }
    }
    __syncthreads();
    for (int i = t; i < NG * C2; i += 256)
        if (psum[i] != 0.f) atomicAdd(&pool[i], psum[i]);
    if (t < NG && cs[t] != 0.f) atomicAdd(&cntf[t], cs[t]);
}

// ---------------- final ----------------
__global__ void k_final(const float* __restrict__ pool, const float* __restrict__ cntf,
                        const float* __restrict__ lw, const float* __restrict__ lb,
                        float* __restrict__ out)
{
    int g = threadIdx.x;
    if (g < NG) {
        float c = fmaxf(cntf[g], 1.0f);
        float inv = 1.0f / c;
        float s = lb[0];
        #pragma unroll
        for (int k = 0; k < C2; ++k) s = fmaf(pool[g * C2 + k] * inv, lw[k], s);
        out[g] = s;
    }
}

extern "C" void kernel_launch(void* const* d_in, const int* in_sizes, int n_in,
                              void* d_out, int out_size, void* d_ws, size_t ws_size,
                              hipStream_t stream) {
    const float* x     = (const float*)d_in[0];
    const int*   ei    = (const int*)d_in[1];
    const int*   batch = (const int*)d_in[2];
    const float* W1    = (const float*)d_in[3];
    const float* b1    = (const float*)d_in[4];
    const float* W2    = (const float*)d_in[5];
    const float* b2    = (const float*)d_in[6];
    const float* lw    = (const float*)d_in[7];
    const float* lb    = (const float*)d_in[8];
    float* out = (float*)d_out;

    float*    wsf = (float*)d_ws;
    int*      wsi = (int*)d_ws;
    unsigned* wsu = (unsigned*)d_ws;

    int*      runstart = wsi + OFF_RUN;
    float*    dis      = wsf + OFF_DIS;
    float*    pool     = wsf + OFF_POOL;
    float*    cntf     = wsf + OFF_CNTF;
    unsigned* edgebuf  = wsu + OFF_EDG;
    unsigned* xs1h0    = wsu + OFF_XS1H0;
    unsigned* xs1h1    = wsu + OFF_XS1H1;
    float*    h1h0     = wsf + OFF_H1H0;
    unsigned* xs2b     = wsu + OFF_XS2B;

    const int* S = ei;            // edge_index[0] (src)
    const int* D = ei + NE;       // edge_index[1] (dst)

    hipMemsetAsync(pool, 0, (NG * C2 + NG) * sizeof(float), stream);

    k_part    <<<NW, 256, 0, stream>>>(S, D, edgebuf, runstart);
    k_nodeinfo<<<NBKT, 256, 0, stream>>>(edgebuf, runstart, dis);
    k_gemm1   <<<(NN + 127) / 128, 256, 0, stream>>>(x, W1, dis, xs1h0, xs1h1);
    k_agg1<0> <<<NBKT, 256, 0, stream>>>(edgebuf, runstart, xs1h0, dis, b1, h1h0, W2, xs2b);
    k_agg1<1> <<<NBKT, 256, 0, stream>>>(edgebuf, runstart, xs1h1, dis, b1, h1h0, W2, xs2b);
    k_agg2    <<<NBKT, 256, 0, stream>>>(edgebuf, runstart, xs2b, dis, b2, batch, pool, cntf);
    k_final   <<<1, 64, 0, stream>>>(pool, cntf, lw, lb, out);
}

// Round 9
// 303.996 us; speedup vs baseline: 4.0967x; 4.0967x over previous
//
#include <hip/hip_runtime.h>

#define NN 100000
#define NE 3200000
#define NF 128
#define C1 32
#define C2 16
#define NG 64
#define BKT_SH 7
#define BKT_W  128
#define NBKT   782          // ceil(NN/128)
#define CH     8192         // edges per partition chunk
#define NW     391          // ceil(NE/CH)
#define RSTR   784          // runstart row stride (783 used)
#define MAPCAP 6400         // per-bucket flattened-edge capacity (mean 4092, sd 64)

// ---- workspace layout (4-byte element offsets) ----
#define OFF_BCNT  0            // 1024 ints (782 used)
#define OFF_BST   1024         // 1024 ints (783 used)
#define OFF_RUN   2048         // NW*RSTR = 306,544 ints
#define OFF_ROW   308608       // NN+1 ints
#define OFF_DIS   408624       // NN floats
#define OFF_POOL  508624       // NG*C2 floats
#define OFF_CNTF  509648       // NG floats (+pad)
#define OFF_EDG   509712       // NE uints (dead after fillfused)
#define OFF_XS1H0 OFF_EDG                  // NN*8 uints bf16x2 cols 0..15 (aliases edgebuf)
#define OFF_XS1H1 (OFF_EDG + NN*8)         // NN*8 uints cols 16..31 (aliases edgebuf)
#define OFF_H1A   (OFF_EDG + NE)           // NN*16 floats (h1 cols 0..15)
#define OFF_H1B   (OFF_H1A + NN*16)        // NN*16 floats (h1 cols 16..31)
#define OFF_XS2B  (OFF_H1B + NN*16)        // NN*8 uints bf16x2
#define OFF_COL   (OFF_XS2B + NN*8)        // NE ints CSR col indices

// ---- bf16x2 pack/unpack (RNE) ----
__device__ __forceinline__ unsigned pack_bf2(float a, float b) {
    unsigned ua = __float_as_uint(a);
    unsigned ub = __float_as_uint(b);
    ua = (ua + 0x7fffu + ((ua >> 16) & 1u)) >> 16;
    ub = (ub + 0x7fffu + ((ub >> 16) & 1u)) & 0xffff0000u;
    return ua | ub;   // lo = a, hi = b
}
__device__ __forceinline__ float2 unpack_bf2(unsigned u) {
    return make_float2(__uint_as_float(u << 16), __uint_as_float(u & 0xffff0000u));
}

// ---------------- k_part: per-chunk counting sort by bucket -----------------
__global__ __launch_bounds__(256) void k_part(
    const int* __restrict__ S, const int* __restrict__ D,
    unsigned* __restrict__ edgebuf, int* __restrict__ runstart,
    int* __restrict__ bcnt)
{
    __shared__ int lhist[1024];
    __shared__ int lstart[1024];
    __shared__ int lcur[NBKT];
    __shared__ int sd[256];
    __shared__ unsigned lsort[CH];
    const int w = blockIdx.x;
    const int t = threadIdx.x;
    const int e0 = w * CH;
    const int n = min(CH, NE - e0);

    for (int i = t; i < 1024; i += 256) lhist[i] = 0;
    __syncthreads();
    for (int i = t; i < n; i += 256)
        atomicAdd(&lhist[(unsigned)D[e0 + i] >> BKT_SH], 1);
    __syncthreads();
    for (int i = t; i < NBKT; i += 256) atomicAdd(&bcnt[i], lhist[i]);
    int c0 = lhist[t * 4 + 0], c1 = lhist[t * 4 + 1];
    int c2 = lhist[t * 4 + 2], c3 = lhist[t * 4 + 3];
    int ts = c0 + c1 + c2 + c3;
    sd[t] = ts;
    __syncthreads();
    for (int off = 1; off < 256; off <<= 1) {
        int v = (t >= off) ? sd[t - off] : 0;
        __syncthreads();
        sd[t] += v;
        __syncthreads();
    }
    int excl = sd[t] - ts;
    lstart[t * 4 + 0] = excl;
    lstart[t * 4 + 1] = excl + c0;
    lstart[t * 4 + 2] = excl + c0 + c1;
    lstart[t * 4 + 3] = excl + c0 + c1 + c2;
    __syncthreads();
    for (int i = t; i < 783; i += 256) runstart[w * RSTR + i] = lstart[i];
    for (int i = t; i < NBKT; i += 256) lcur[i] = lstart[i];
    __syncthreads();
    for (int i = t; i < n; i += 256) {
        int s = S[e0 + i], d = D[e0 + i];
        int pos = atomicAdd(&lcur[(unsigned)d >> BKT_SH], 1);
        lsort[pos] = ((unsigned)s << BKT_SH) | (unsigned)(d & (BKT_W - 1));
    }
    __syncthreads();
    for (int i = t; i < n; i += 256) edgebuf[e0 + i] = lsort[i];
}

// ---------------- scan 782 bucket totals (single WG) ----------------
__global__ __launch_bounds__(256) void k_bscan(const int* __restrict__ bcnt,
                                               int* __restrict__ bstart,
                                               int* __restrict__ rowstart) {
    __shared__ int sd[256];
    const int t = threadIdx.x;
    const int base = t * 4;
    int c0 = (base + 0 < NBKT) ? bcnt[base + 0] : 0;
    int c1 = (base + 1 < NBKT) ? bcnt[base + 1] : 0;
    int c2 = (base + 2 < NBKT) ? bcnt[base + 2] : 0;
    int c3 = (base + 3 < NBKT) ? bcnt[base + 3] : 0;
    int ts = c0 + c1 + c2 + c3;
    sd[t] = ts;
    __syncthreads();
    for (int off = 1; off < 256; off <<= 1) {
        int v = (t >= off) ? sd[t - off] : 0;
        __syncthreads();
        sd[t] += v;
        __syncthreads();
    }
    int excl = sd[t] - ts;
    if (base + 0 < 783) bstart[base + 0] = excl;
    if (base + 1 < 783) bstart[base + 1] = excl + c0;
    if (base + 2 < 783) bstart[base + 2] = excl + c0 + c1;
    if (base + 3 < 783) bstart[base + 3] = excl + c0 + c1 + c2;
    if (t == 0) rowstart[NN] = NE;
}

// ---------------- fused per-bucket fill (flattened edge index) --------------
__global__ __launch_bounds__(256) void k_fillfused(
    const unsigned* __restrict__ edgebuf, const int* __restrict__ runstart,
    const int* __restrict__ bstart,
    int* __restrict__ rowstart, float* __restrict__ dis, int* __restrict__ colidx)
{
    __shared__ int rl[NW];
    __shared__ int pfx[NW];
    __shared__ int basea[NW];
    __shared__ unsigned short map[MAPCAP];
    __shared__ int lcnt[BKT_W];
    __shared__ int lcur[BKT_W];
    __shared__ int sd[256];
    const int b = blockIdx.x;
    const int t = threadIdx.x;
    const int bs = bstart[b];
    const int total = bstart[b + 1] - bs;

    for (int w = t; w < NW; w += 256) {
        int s0 = runstart[w * RSTR + b];
        int s1 = runstart[w * RSTR + b + 1];
        basea[w] = s0;
        rl[w] = s1 - s0;
    }
    if (t < BKT_W) lcnt[t] = 0;
    __syncthreads();
    {
        int w0 = t * 2;
        int c0 = (w0 < NW) ? rl[w0] : 0;
        int c1 = (w0 + 1 < NW) ? rl[w0 + 1] : 0;
        int ts = c0 + c1;
        sd[t] = ts;
        __syncthreads();
        for (int off = 1; off < 256; off <<= 1) {
            int v = (t >= off) ? sd[t - off] : 0;
            __syncthreads();
            sd[t] += v;
            __syncthreads();
        }
        int excl = sd[t] - ts;
        if (w0 < NW)     pfx[w0]     = excl;
        if (w0 + 1 < NW) pfx[w0 + 1] = excl + c0;
    }
    __syncthreads();
    for (int w = t; w < NW; w += 256) {
        int p = pfx[w], len = rl[w];
        basea[w] = w * CH + basea[w] - p;
        for (int i = 0; i < len; ++i) map[p + i] = (unsigned short)w;
    }
    __syncthreads();
    for (int j = t; j < total; j += 256) {
        unsigned p = edgebuf[basea[map[j]] + j];
        atomicAdd(&lcnt[p & (BKT_W - 1)], 1);
    }
    __syncthreads();
    if (t < BKT_W) lcur[t] = lcnt[t];
    __syncthreads();
    for (int off = 1; off < BKT_W; off <<= 1) {
        int v = (t < BKT_W && t >= off) ? lcur[t - off] : 0;
        __syncthreads();
        if (t < BKT_W) lcur[t] += v;
        __syncthreads();
    }
    if (t < BKT_W) {
        int excl = lcur[t] - lcnt[t];
        int node = b * BKT_W + t;
        if (node < NN) {
            rowstart[node] = bs + excl;
            dis[node] = rsqrtf((float)lcnt[t] + 1.0f);
        }
        lcur[t] = bs + excl;
    }
    __syncthreads();
    for (int j = t; j < total; j += 256) {
        unsigned p = edgebuf[basea[map[j]] + j];
        int pos = atomicAdd(&lcur[p & (BKT_W - 1)], 1);
        colidx[pos] = (int)(p >> BKT_SH);
    }
}

// ---------------- GEMM1: xs1h{0,1} = bf16x2{(x @ W1) * dis} -----------------
__global__ __launch_bounds__(256) void k_gemm1(
    const float* __restrict__ x, const float* __restrict__ W1,
    const float* __restrict__ dis,
    unsigned* __restrict__ xs1h0, unsigned* __restrict__ xs1h1)
{
    __shared__ float xls[128 * 33];
    __shared__ float wls[32 * 32];
    const int t = threadIdx.x;
    const int tc = t & 7;
    const int tr = t >> 3;
    const int base = blockIdx.x * 128;

    float a[4][4] = {};

    for (int k0 = 0; k0 < NF; k0 += 32) {
        {
            int i = t * 4;
            int kk = i >> 5, c = i & 31;
            *(float4*)&wls[kk * 32 + c] = *(const float4*)&W1[(k0 + kk) * C1 + c];
        }
        #pragma unroll
        for (int r = 0; r < 4; ++r) {
            int n = (t >> 3) + r * 32;
            int j = (t & 7) * 4;
            int node = base + n;
            float4 v = make_float4(0.f, 0.f, 0.f, 0.f);
            if (node < NN) v = *(const float4*)&x[(long long)node * NF + k0 + j];
            xls[n * 33 + j + 0] = v.x;
            xls[n * 33 + j + 1] = v.y;
            xls[n * 33 + j + 2] = v.z;
            xls[n * 33 + j + 3] = v.w;
        }
        __syncthreads();
        #pragma unroll 8
        for (int kk = 0; kk < 32; ++kk) {
            float4 w = *(const float4*)&wls[kk * 32 + tc * 4];
            #pragma unroll
            for (int i = 0; i < 4; ++i) {
                float xv = xls[(tr * 4 + i) * 33 + kk];
                a[i][0] = fmaf(xv, w.x, a[i][0]);
                a[i][1] = fmaf(xv, w.y, a[i][1]);
                a[i][2] = fmaf(xv, w.z, a[i][2]);
                a[i][3] = fmaf(xv, w.w, a[i][3]);
            }
        }
        __syncthreads();
    }
    #pragma unroll
    for (int i = 0; i < 4; ++i) {
        int node = base + tr * 4 + i;
        if (node < NN) {
            float dv = dis[node];
            uint2 o;
            o.x = pack_bf2(a[i][0] * dv, a[i][1] * dv);
            o.y = pack_bf2(a[i][2] * dv, a[i][3] * dv);
            unsigned* dst = (tc < 4) ? &xs1h0[node * 8 + tc * 2]
                                     : &xs1h1[node * 8 + (tc - 4) * 2];
            *(uint2*)dst = o;
        }
    }
}

// ---------------- gather layer1 half: 8 lanes/node, 2 cols/lane -------------
// Two sequential dispatches; each pass's xs half (3.2 MB) is per-XCD L2-resident.
template<int HALF>
__global__ __launch_bounds__(256) void k_gather1h(
    const unsigned* __restrict__ xsh, const int* __restrict__ colidx,
    const int* __restrict__ rowstart, const float* __restrict__ dis,
    const float* __restrict__ b1, float* __restrict__ h1h)
{
    const int l = threadIdx.x & 7;
    const int v = blockIdx.x * 32 + (threadIdx.x >> 3);
    if (v >= NN) return;
    const int start = rowstart[v];
    const int num = rowstart[v + 1] - start;
    const int* __restrict__ cp = &colidx[start];

    float2 a0 = unpack_bf2(xsh[v * 8 + l]);  // self loop
    float2 a1 = make_float2(0.f, 0.f), a2 = a1, a3 = a1;
    int i = 0;
    for (; i + 4 <= num; i += 4) {
        int s0 = cp[i], s1 = cp[i + 1], s2 = cp[i + 2], s3 = cp[i + 3];
        float2 u0 = unpack_bf2(xsh[s0 * 8 + l]);
        float2 u1 = unpack_bf2(xsh[s1 * 8 + l]);
        float2 u2 = unpack_bf2(xsh[s2 * 8 + l]);
        float2 u3 = unpack_bf2(xsh[s3 * 8 + l]);
        a0.x += u0.x; a0.y += u0.y;
        a1.x += u1.x; a1.y += u1.y;
        a2.x += u2.x; a2.y += u2.y;
        a3.x += u3.x; a3.y += u3.y;
    }
    for (; i < num; ++i) {
        float2 u = unpack_bf2(xsh[cp[i] * 8 + l]);
        a0.x += u.x; a0.y += u.y;
    }
    float accx = (a0.x + a1.x) + (a2.x + a3.x);
    float accy = (a0.y + a1.y) + (a2.y + a3.y);
    float dv = dis[v];
    float2 bv = *(const float2*)&b1[HALF * 16 + l * 2];
    float2 o;
    o.x = fmaxf(fmaf(accx, dv, bv.x), 0.f);
    o.y = fmaxf(fmaf(accy, dv, bv.y), 0.f);
    *(float2*)&h1h[v * 16 + l * 2] = o;
}

// ---------------- GEMM2: xs2b = bf16x2{(h1 @ W2) * dis} ----------------
__global__ __launch_bounds__(256) void k_gemm2(
    const float* __restrict__ h1a, const float* __restrict__ h1b,
    const float* __restrict__ W2,
    const float* __restrict__ dis, unsigned* __restrict__ xs2b)
{
    __shared__ float hls[128 * 33];
    __shared__ float wls[32 * 16];
    const int t = threadIdx.x;
    const int base = blockIdx.x * 128;

    if (t < 128) *(float4*)&wls[t * 4] = *(const float4*)&W2[t * 4];

    #pragma unroll
    for (int r = 0; r < 4; ++r) {
        int n = (t >> 3) + r * 32;
        int j = (t & 7) * 4;
        int node = base + n;
        float4 v = make_float4(0.f, 0.f, 0.f, 0.f);
        if (node < NN) {
            v = (j < 16) ? *(const float4*)&h1a[node * 16 + j]
                         : *(const float4*)&h1b[node * 16 + (j - 16)];
        }
        hls[n * 33 + j + 0] = v.x;
        hls[n * 33 + j + 1] = v.y;
        hls[n * 33 + j + 2] = v.z;
        hls[n * 33 + j + 3] = v.w;
    }
    __syncthreads();

    const int tc = t & 3;
    const int tr = t >> 2;
    float a[2][4] = {};
    #pragma unroll 8
    for (int kk = 0; kk < 32; ++kk) {
        float4 w = *(const float4*)&wls[kk * C2 + tc * 4];
        #pragma unroll
        for (int i = 0; i < 2; ++i) {
            float xv = hls[(tr * 2 + i) * 33 + kk];
            a[i][0] = fmaf(xv, w.x, a[i][0]);
            a[i][1] = fmaf(xv, w.y, a[i][1]);
            a[i][2] = fmaf(xv, w.z, a[i][2]);
            a[i][3] = fmaf(xv, w.w, a[i][3]);
        }
    }
    #pragma unroll
    for (int i = 0; i < 2; ++i) {
        int node = base + tr * 2 + i;
        if (node < NN) {
            float dv = dis[node];
            uint2 o;
            o.x = pack_bf2(a[i][0] * dv, a[i][1] * dv);
            o.y = pack_bf2(a[i][2] * dv, a[i][3] * dv);
            *(uint2*)&xs2b[node * 8 + tc * 2] = o;
        }
    }
}

// ---------------- gather layer2 + fused mean-pool ----------------
// 8 lanes/node, 32 nodes/block; h2 never materialized.
__global__ __launch_bounds__(256) void k_gather2(
    const unsigned* __restrict__ xs2b, const int* __restrict__ colidx,
    const int* __restrict__ rowstart, const float* __restrict__ dis,
    const float* __restrict__ b2, const int* __restrict__ batch,
    float* __restrict__ pool, float* __restrict__ cntf)
{
    __shared__ float psum[NG * C2];
    __shared__ float cs[NG];
    const int t = threadIdx.x;
    for (int i = t; i < NG * C2; i += 256) psum[i] = 0.f;
    if (t < NG) cs[t] = 0.f;
    __syncthreads();

    const int l = t & 7;
    const int v = blockIdx.x * 32 + (t >> 3);
    if (v < NN) {
        const int start = rowstart[v];
        const int num = rowstart[v + 1] - start;
        const int* __restrict__ cp = &colidx[start];

        float2 a0 = unpack_bf2(xs2b[v * 8 + l]);  // self loop
        float2 a1 = make_float2(0.f, 0.f), a2 = a1, a3 = a1;
        int i = 0;
        for (; i + 4 <= num; i += 4) {
            int s0 = cp[i], s1 = cp[i + 1], s2 = cp[i + 2], s3 = cp[i + 3];
            float2 u0 = unpack_bf2(xs2b[s0 * 8 + l]);
            float2 u1 = unpack_bf2(xs2b[s1 * 8 + l]);
            float2 u2 = unpack_bf2(xs2b[s2 * 8 + l]);
            float2 u3 = unpack_bf2(xs2b[s3 * 8 + l]);
            a0.x += u0.x; a0.y += u0.y;
            a1.x += u1.x; a1.y += u1.y;
            a2.x += u2.x; a2.y += u2.y;
            a3.x += u3.x; a3.y += u3.y;
        }
        for (; i < num; ++i) {
            float2 u = unpack_bf2(xs2b[cp[i] * 8 + l]);
            a0.x += u.x; a0.y += u.y;
        }
        float accx = (a0.x + a1.x) + (a2.x + a3.x);
        float accy = (a0.y + a1.y) + (a2.y + a3.y);
        float dv = dis[v];
        float2 bv = *(const float2*)&b2[l * 2];
        int g = batch[v];
        atomicAdd(&psum[g * C2 + l * 2],     fmaf(accx, dv, bv.x));
        atomicAdd(&psum[g * C2 + l * 2 + 1], fmaf(accy, dv, bv.y));
        if (l == 0) atomicAdd(&cs[g], 1.0f);
    }
    __syncthreads();
    for (int i = t; i < NG * C2; i += 256)
        if (psum[i] != 0.f) atomicAdd(&pool[i], psum[i]);
    if (t < NG && cs[t] != 0.f) atomicAdd(&cntf[t], cs[t]);
}

// ---------------- final ----------------
__global__ void k_final(const float* __restrict__ pool, const float* __restrict__ cntf,
                        const float* __restrict__ lw, const float* __restrict__ lb,
                        float* __restrict__ out)
{
    int g = threadIdx.x;
    if (g < NG) {
        float c = fmaxf(cntf[g], 1.0f);
        float inv = 1.0f / c;
        float s = lb[0];
        #pragma unroll
        for (int k = 0; k < C2; ++k) s = fmaf(pool[g * C2 + k] * inv, lw[k], s);
        out[g] = s;
    }
}

extern "C" void kernel_launch(void* const* d_in, const int* in_sizes, int n_in,
                              void* d_out, int out_size, void* d_ws, size_t ws_size,
                              hipStream_t stream) {
    const float* x     = (const float*)d_in[0];
    const int*   ei    = (const int*)d_in[1];
    const int*   batch = (const int*)d_in[2];
    const float* W1    = (const float*)d_in[3];
    const float* b1    = (const float*)d_in[4];
    const float* W2    = (const float*)d_in[5];
    const float* b2    = (const float*)d_in[6];
    const float* lw    = (const float*)d_in[7];
    const float* lb    = (const float*)d_in[8];
    float* out = (float*)d_out;

    float*    wsf = (float*)d_ws;
    int*      wsi = (int*)d_ws;
    unsigned* wsu = (unsigned*)d_ws;

    int*      bcnt     = wsi + OFF_BCNT;
    int*      bstart   = wsi + OFF_BST;
    int*      runstart = wsi + OFF_RUN;
    int*      rowstart = wsi + OFF_ROW;
    float*    dis      = wsf + OFF_DIS;
    float*    pool     = wsf + OFF_POOL;
    float*    cntf     = wsf + OFF_CNTF;
    unsigned* edgebuf  = wsu + OFF_EDG;
    unsigned* xs1h0    = wsu + OFF_XS1H0;  // aliases edgebuf (dead after fillfused)
    unsigned* xs1h1    = wsu + OFF_XS1H1;
    float*    h1a      = wsf + OFF_H1A;
    float*    h1b      = wsf + OFF_H1B;
    unsigned* xs2b     = wsu + OFF_XS2B;
    int*      colidx   = wsi + OFF_COL;

    const int* S = ei;            // edge_index[0] (src)
    const int* D = ei + NE;       // edge_index[1] (dst)

    hipMemsetAsync(bcnt, 0, 1024 * sizeof(int), stream);
    hipMemsetAsync(pool, 0, (NG * C2 + NG) * sizeof(float), stream);

    k_part      <<<NW, 256, 0, stream>>>(S, D, edgebuf, runstart, bcnt);
    k_bscan     <<<1, 256, 0, stream>>>(bcnt, bstart, rowstart);
    k_fillfused <<<NBKT, 256, 0, stream>>>(edgebuf, runstart, bstart, rowstart, dis, colidx);
    k_gemm1     <<<(NN + 127) / 128, 256, 0, stream>>>(x, W1, dis, xs1h0, xs1h1);
    k_gather1h<0><<<(NN + 31) / 32, 256, 0, stream>>>(xs1h0, colidx, rowstart, dis, b1, h1a);
    k_gather1h<1><<<(NN + 31) / 32, 256, 0, stream>>>(xs1h1, colidx, rowstart, dis, b1, h1b);
    k_gemm2     <<<(NN + 127) / 128, 256, 0, stream>>>(h1a, h1b, W2, dis, xs2b);
    k_gather2   <<<(NN + 31) / 32, 256, 0, stream>>>(xs2b, colidx, rowstart, dis, b2, batch, pool, cntf);
    k_final     <<<1, 64, 0, stream>>>(pool, cntf, lw, lb, out);
}

// Round 10
// 280.230 us; speedup vs baseline: 4.4441x; 1.0848x over previous
//
#include <hip/hip_runtime.h>

#define NN 100000
#define NE 3200000
#define NF 128
#define C1 32
#define C2 16
#define NG 64
#define BKT_SH 7
#define BKT_W  128
#define NBKT   782          // ceil(NN/128)
#define CH     8192         // edges per partition chunk
#define NW     391          // ceil(NE/CH)
#define RSTR   784          // runstart row stride (783 used)
#define MAPCAP 6400         // per-bucket flattened-edge capacity (mean 4092, sd 64)

// ---- workspace layout (4-byte element offsets) ----
#define OFF_BCNT  0            // 1024 ints (782 used)
#define OFF_BST   1024         // 1024 ints (783 used)
#define OFF_RUN   2048         // NW*RSTR = 306,544 ints
#define OFF_ROW   308608       // NN+1 ints
#define OFF_DIS   408624       // NN floats
#define OFF_POOL  508624       // NG*C2 floats
#define OFF_CNTF  509648       // NG floats (+pad)
#define OFF_EDG   509712       // NE uints (dead after fillfused)
#define OFF_XS1H0 OFF_EDG                  // NN*8 uints bf16x2 cols 0..15 (aliases edgebuf)
#define OFF_XS1H1 (OFF_EDG + NN*8)         // NN*8 uints cols 16..31 (aliases edgebuf)
#define OFF_H1A   (OFF_EDG + NE)           // NN*16 floats (h1 cols 0..15)
#define OFF_XS2B  (OFF_H1A + NN*16)        // NN*8 uints bf16x2
#define OFF_COL   (OFF_XS2B + NN*8)        // NE ints CSR col indices

// ---- bf16x2 pack/unpack (RNE) ----
__device__ __forceinline__ unsigned pack_bf2(float a, float b) {
    unsigned ua = __float_as_uint(a);
    unsigned ub = __float_as_uint(b);
    ua = (ua + 0x7fffu + ((ua >> 16) & 1u)) >> 16;
    ub = (ub + 0x7fffu + ((ub >> 16) & 1u)) & 0xffff0000u;
    return ua | ub;   // lo = a, hi = b
}
__device__ __forceinline__ float2 unpack_bf2(unsigned u) {
    return make_float2(__uint_as_float(u << 16), __uint_as_float(u & 0xffff0000u));
}
__device__ __forceinline__ void acc4(float4& a, uint2 q) {
    float2 f0 = unpack_bf2(q.x), f1 = unpack_bf2(q.y);
    a.x += f0.x; a.y += f0.y; a.z += f1.x; a.w += f1.y;
}

// ---------------- k_part: per-chunk counting sort by bucket -----------------
__global__ __launch_bounds__(256) void k_part(
    const int* __restrict__ S, const int* __restrict__ D,
    unsigned* __restrict__ edgebuf, int* __restrict__ runstart,
    int* __restrict__ bcnt)
{
    __shared__ int lhist[1024];
    __shared__ int lstart[1024];
    __shared__ int lcur[NBKT];
    __shared__ int sd[256];
    __shared__ unsigned lsort[CH];
    const int w = blockIdx.x;
    const int t = threadIdx.x;
    const int e0 = w * CH;
    const int n = min(CH, NE - e0);

    for (int i = t; i < 1024; i += 256) lhist[i] = 0;
    __syncthreads();
    for (int i = t; i < n; i += 256)
        atomicAdd(&lhist[(unsigned)D[e0 + i] >> BKT_SH], 1);
    __syncthreads();
    for (int i = t; i < NBKT; i += 256) atomicAdd(&bcnt[i], lhist[i]);
    int c0 = lhist[t * 4 + 0], c1 = lhist[t * 4 + 1];
    int c2 = lhist[t * 4 + 2], c3 = lhist[t * 4 + 3];
    int ts = c0 + c1 + c2 + c3;
    sd[t] = ts;
    __syncthreads();
    for (int off = 1; off < 256; off <<= 1) {
        int v = (t >= off) ? sd[t - off] : 0;
        __syncthreads();
        sd[t] += v;
        __syncthreads();
    }
    int excl = sd[t] - ts;
    lstart[t * 4 + 0] = excl;
    lstart[t * 4 + 1] = excl + c0;
    lstart[t * 4 + 2] = excl + c0 + c1;
    lstart[t * 4 + 3] = excl + c0 + c1 + c2;
    __syncthreads();
    for (int i = t; i < 783; i += 256) runstart[w * RSTR + i] = lstart[i];
    for (int i = t; i < NBKT; i += 256) lcur[i] = lstart[i];
    __syncthreads();
    for (int i = t; i < n; i += 256) {
        int s = S[e0 + i], d = D[e0 + i];
        int pos = atomicAdd(&lcur[(unsigned)d >> BKT_SH], 1);
        lsort[pos] = ((unsigned)s << BKT_SH) | (unsigned)(d & (BKT_W - 1));
    }
    __syncthreads();
    for (int i = t; i < n; i += 256) edgebuf[e0 + i] = lsort[i];
}

// ---------------- scan 782 bucket totals (single WG) ----------------
__global__ __launch_bounds__(256) void k_bscan(const int* __restrict__ bcnt,
                                               int* __restrict__ bstart,
                                               int* __restrict__ rowstart) {
    __shared__ int sd[256];
    const int t = threadIdx.x;
    const int base = t * 4;
    int c0 = (base + 0 < NBKT) ? bcnt[base + 0] : 0;
    int c1 = (base + 1 < NBKT) ? bcnt[base + 1] : 0;
    int c2 = (base + 2 < NBKT) ? bcnt[base + 2] : 0;
    int c3 = (base + 3 < NBKT) ? bcnt[base + 3] : 0;
    int ts = c0 + c1 + c2 + c3;
    sd[t] = ts;
    __syncthreads();
    for (int off = 1; off < 256; off <<= 1) {
        int v = (t >= off) ? sd[t - off] : 0;
        __syncthreads();
        sd[t] += v;
        __syncthreads();
    }
    int excl = sd[t] - ts;
    if (base + 0 < 783) bstart[base + 0] = excl;
    if (base + 1 < 783) bstart[base + 1] = excl + c0;
    if (base + 2 < 783) bstart[base + 2] = excl + c0 + c1;
    if (base + 3 < 783) bstart[base + 3] = excl + c0 + c1 + c2;
    if (t == 0) rowstart[NN] = NE;
}

// ---------------- fused per-bucket fill (flattened edge index) --------------
__global__ __launch_bounds__(256) void k_fillfused(
    const unsigned* __restrict__ edgebuf, const int* __restrict__ runstart,
    const int* __restrict__ bstart,
    int* __restrict__ rowstart, float* __restrict__ dis, int* __restrict__ colidx)
{
    __shared__ int rl[NW];
    __shared__ int pfx[NW];
    __shared__ int basea[NW];
    __shared__ unsigned short map[MAPCAP];
    __shared__ int lcnt[BKT_W];
    __shared__ int lcur[BKT_W];
    __shared__ int sd[256];
    const int b = blockIdx.x;
    const int t = threadIdx.x;
    const int bs = bstart[b];
    const int total = bstart[b + 1] - bs;

    for (int w = t; w < NW; w += 256) {
        int s0 = runstart[w * RSTR + b];
        int s1 = runstart[w * RSTR + b + 1];
        basea[w] = s0;
        rl[w] = s1 - s0;
    }
    if (t < BKT_W) lcnt[t] = 0;
    __syncthreads();
    {
        int w0 = t * 2;
        int c0 = (w0 < NW) ? rl[w0] : 0;
        int c1 = (w0 + 1 < NW) ? rl[w0 + 1] : 0;
        int ts = c0 + c1;
        sd[t] = ts;
        __syncthreads();
        for (int off = 1; off < 256; off <<= 1) {
            int v = (t >= off) ? sd[t - off] : 0;
            __syncthreads();
            sd[t] += v;
            __syncthreads();
        }
        int excl = sd[t] - ts;
        if (w0 < NW)     pfx[w0]     = excl;
        if (w0 + 1 < NW) pfx[w0 + 1] = excl + c0;
    }
    __syncthreads();
    for (int w = t; w < NW; w += 256) {
        int p = pfx[w], len = rl[w];
        basea[w] = w * CH + basea[w] - p;
        for (int i = 0; i < len; ++i) map[p + i] = (unsigned short)w;
    }
    __syncthreads();
    for (int j = t; j < total; j += 256) {
        unsigned p = edgebuf[basea[map[j]] + j];
        atomicAdd(&lcnt[p & (BKT_W - 1)], 1);
    }
    __syncthreads();
    if (t < BKT_W) lcur[t] = lcnt[t];
    __syncthreads();
    for (int off = 1; off < BKT_W; off <<= 1) {
        int v = (t < BKT_W && t >= off) ? lcur[t - off] : 0;
        __syncthreads();
        if (t < BKT_W) lcur[t] += v;
        __syncthreads();
    }
    if (t < BKT_W) {
        int excl = lcur[t] - lcnt[t];
        int node = b * BKT_W + t;
        if (node < NN) {
            rowstart[node] = bs + excl;
            dis[node] = rsqrtf((float)lcnt[t] + 1.0f);
        }
        lcur[t] = bs + excl;
    }
    __syncthreads();
    for (int j = t; j < total; j += 256) {
        unsigned p = edgebuf[basea[map[j]] + j];
        int pos = atomicAdd(&lcur[p & (BKT_W - 1)], 1);
        colidx[pos] = (int)(p >> BKT_SH);
    }
}

// ---------------- GEMM1: xs1h{0,1} = bf16x2{(x @ W1) * dis} -----------------
__global__ __launch_bounds__(256) void k_gemm1(
    const float* __restrict__ x, const float* __restrict__ W1,
    const float* __restrict__ dis,
    unsigned* __restrict__ xs1h0, unsigned* __restrict__ xs1h1)
{
    __shared__ float xls[128 * 33];
    __shared__ float wls[32 * 32];
    const int t = threadIdx.x;
    const int tc = t & 7;
    const int tr = t >> 3;
    const int base = blockIdx.x * 128;

    float a[4][4] = {};

    for (int k0 = 0; k0 < NF; k0 += 32) {
        {
            int i = t * 4;
            int kk = i >> 5, c = i & 31;
            *(float4*)&wls[kk * 32 + c] = *(const float4*)&W1[(k0 + kk) * C1 + c];
        }
        #pragma unroll
        for (int r = 0; r < 4; ++r) {
            int n = (t >> 3) + r * 32;
            int j = (t & 7) * 4;
            int node = base + n;
            float4 v = make_float4(0.f, 0.f, 0.f, 0.f);
            if (node < NN) v = *(const float4*)&x[(long long)node * NF + k0 + j];
            xls[n * 33 + j + 0] = v.x;
            xls[n * 33 + j + 1] = v.y;
            xls[n * 33 + j + 2] = v.z;
            xls[n * 33 + j + 3] = v.w;
        }
        __syncthreads();
        #pragma unroll 8
        for (int kk = 0; kk < 32; ++kk) {
            float4 w = *(const float4*)&wls[kk * 32 + tc * 4];
            #pragma unroll
            for (int i = 0; i < 4; ++i) {
                float xv = xls[(tr * 4 + i) * 33 + kk];
                a[i][0] = fmaf(xv, w.x, a[i][0]);
                a[i][1] = fmaf(xv, w.y, a[i][1]);
                a[i][2] = fmaf(xv, w.z, a[i][2]);
                a[i][3] = fmaf(xv, w.w, a[i][3]);
            }
        }
        __syncthreads();
    }
    #pragma unroll
    for (int i = 0; i < 4; ++i) {
        int node = base + tr * 4 + i;
        if (node < NN) {
            float dv = dis[node];
            uint2 o;
            o.x = pack_bf2(a[i][0] * dv, a[i][1] * dv);
            o.y = pack_bf2(a[i][2] * dv, a[i][3] * dv);
            unsigned* dst = (tc < 4) ? &xs1h0[node * 8 + tc * 2]
                                     : &xs1h1[node * 8 + (tc - 4) * 2];
            *(uint2*)dst = o;
        }
    }
}

// ---------------- gather layer1 half: 4 lanes/node, uint2 loads, 8-unroll ---
// HALF 0: h1a = relu(dis*agg + b1[0:16]).
// HALF 1: fused GEMM2 epilogue — stage full h1 row in LDS, emit xs2b.
template<int HALF>
__global__ __launch_bounds__(256) void k_gather1h(
    const unsigned* __restrict__ xsh, const int* __restrict__ colidx,
    const int* __restrict__ rowstart, const float* __restrict__ dis,
    const float* __restrict__ b1, float* __restrict__ h1a,
    const float* __restrict__ W2, unsigned* __restrict__ xs2b)
{
    __shared__ float w2s[C1 * C2];
    __shared__ float hrow[64 * 33];
    const int t = threadIdx.x;
    if (HALF == 1 && t < 128) *(float4*)&w2s[t * 4] = *(const float4*)&W2[t * 4];
    const int l = t & 3;
    const int n = t >> 2;
    const int v = blockIdx.x * 64 + n;
    const bool valid = v < NN;

    float4 acc = make_float4(0.f, 0.f, 0.f, 0.f);
    float dv = 0.f;
    if (valid) {
        const int start = rowstart[v];
        const int num = rowstart[v + 1] - start;
        const int* __restrict__ cp = &colidx[start];
        uint2 u = *(const uint2*)&xsh[v * 8 + l * 2];   // self loop
        float4 a0 = make_float4(0.f, 0.f, 0.f, 0.f);
        acc4(a0, u);
        float4 a1 = make_float4(0.f, 0.f, 0.f, 0.f), a2 = a1, a3 = a1;
        int i = 0;
        for (; i + 8 <= num; i += 8) {
            int s0 = cp[i], s1 = cp[i+1], s2 = cp[i+2], s3 = cp[i+3];
            int s4 = cp[i+4], s5 = cp[i+5], s6 = cp[i+6], s7 = cp[i+7];
            uint2 q0 = *(const uint2*)&xsh[s0 * 8 + l * 2];
            uint2 q1 = *(const uint2*)&xsh[s1 * 8 + l * 2];
            uint2 q2 = *(const uint2*)&xsh[s2 * 8 + l * 2];
            uint2 q3 = *(const uint2*)&xsh[s3 * 8 + l * 2];
            uint2 q4 = *(const uint2*)&xsh[s4 * 8 + l * 2];
            uint2 q5 = *(const uint2*)&xsh[s5 * 8 + l * 2];
            uint2 q6 = *(const uint2*)&xsh[s6 * 8 + l * 2];
            uint2 q7 = *(const uint2*)&xsh[s7 * 8 + l * 2];
            acc4(a0, q0); acc4(a1, q1); acc4(a2, q2); acc4(a3, q3);
            acc4(a0, q4); acc4(a1, q5); acc4(a2, q6); acc4(a3, q7);
        }
        for (; i < num; ++i) {
            uint2 q = *(const uint2*)&xsh[cp[i] * 8 + l * 2];
            acc4(a0, q);
        }
        acc.x = (a0.x + a1.x) + (a2.x + a3.x);
        acc.y = (a0.y + a1.y) + (a2.y + a3.y);
        acc.z = (a0.z + a1.z) + (a2.z + a3.z);
        acc.w = (a0.w + a1.w) + (a2.w + a3.w);
        dv = dis[v];
    }

    if (HALF == 0) {
        if (valid) {
            float4 o;
            o.x = fmaxf(fmaf(acc.x, dv, b1[l * 4 + 0]), 0.f);
            o.y = fmaxf(fmaf(acc.y, dv, b1[l * 4 + 1]), 0.f);
            o.z = fmaxf(fmaf(acc.z, dv, b1[l * 4 + 2]), 0.f);
            o.w = fmaxf(fmaf(acc.w, dv, b1[l * 4 + 3]), 0.f);
            *(float4*)&h1a[v * 16 + l * 4] = o;
        }
    } else {
        if (valid) {
            float4 hh = *(const float4*)&h1a[v * 16 + l * 4];   // cols 0..15
            hrow[n * 33 + l * 4 + 0] = hh.x;
            hrow[n * 33 + l * 4 + 1] = hh.y;
            hrow[n * 33 + l * 4 + 2] = hh.z;
            hrow[n * 33 + l * 4 + 3] = hh.w;
            hrow[n * 33 + 16 + l * 4 + 0] = fmaxf(fmaf(acc.x, dv, b1[16 + l * 4 + 0]), 0.f);
            hrow[n * 33 + 16 + l * 4 + 1] = fmaxf(fmaf(acc.y, dv, b1[16 + l * 4 + 1]), 0.f);
            hrow[n * 33 + 16 + l * 4 + 2] = fmaxf(fmaf(acc.z, dv, b1[16 + l * 4 + 2]), 0.f);
            hrow[n * 33 + 16 + l * 4 + 3] = fmaxf(fmaf(acc.w, dv, b1[16 + l * 4 + 3]), 0.f);
        }
        __syncthreads();
        if (valid) {
            const float* hr = &hrow[n * 33];
            float s0 = 0.f, s1 = 0.f, s2 = 0.f, s3 = 0.f;
            #pragma unroll
            for (int k = 0; k < 32; ++k) {
                float hv = hr[k];
                s0 = fmaf(hv, w2s[k * C2 + l * 4 + 0], s0);
                s1 = fmaf(hv, w2s[k * C2 + l * 4 + 1], s1);
                s2 = fmaf(hv, w2s[k * C2 + l * 4 + 2], s2);
                s3 = fmaf(hv, w2s[k * C2 + l * 4 + 3], s3);
            }
            uint2 o;
            o.x = pack_bf2(s0 * dv, s1 * dv);
            o.y = pack_bf2(s2 * dv, s3 * dv);
            *(uint2*)&xs2b[v * 8 + l * 2] = o;
        }
    }
}

// ---------------- gather layer2 + fused mean-pool (no bias; folded in final)-
__global__ __launch_bounds__(256) void k_gather2(
    const unsigned* __restrict__ xs2b, const int* __restrict__ colidx,
    const int* __restrict__ rowstart, const float* __restrict__ dis,
    const int* __restrict__ batch,
    float* __restrict__ pool, float* __restrict__ cntf)
{
    __shared__ float psum[NG * C2];
    __shared__ float cs[NG];
    const int t = threadIdx.x;
    for (int i = t; i < NG * C2; i += 256) psum[i] = 0.f;
    if (t < NG) cs[t] = 0.f;
    __syncthreads();

    const int l = t & 3;
    const int n = t >> 2;
    const int v = blockIdx.x * 64 + n;
    if (v < NN) {
        const int start = rowstart[v];
        const int num = rowstart[v + 1] - start;
        const int* __restrict__ cp = &colidx[start];
        uint2 u = *(const uint2*)&xs2b[v * 8 + l * 2];   // self loop
        float4 a0 = make_float4(0.f, 0.f, 0.f, 0.f);
        acc4(a0, u);
        float4 a1 = make_float4(0.f, 0.f, 0.f, 0.f), a2 = a1, a3 = a1;
        int i = 0;
        for (; i + 8 <= num; i += 8) {
            int s0 = cp[i], s1 = cp[i+1], s2 = cp[i+2], s3 = cp[i+3];
            int s4 = cp[i+4], s5 = cp[i+5], s6 = cp[i+6], s7 = cp[i+7];
            uint2 q0 = *(const uint2*)&xs2b[s0 * 8 + l * 2];
            uint2 q1 = *(const uint2*)&xs2b[s1 * 8 + l * 2];
            uint2 q2 = *(const uint2*)&xs2b[s2 * 8 + l * 2];
            uint2 q3 = *(const uint2*)&xs2b[s3 * 8 + l * 2];
            uint2 q4 = *(const uint2*)&xs2b[s4 * 8 + l * 2];
            uint2 q5 = *(const uint2*)&xs2b[s5 * 8 + l * 2];
            uint2 q6 = *(const uint2*)&xs2b[s6 * 8 + l * 2];
            uint2 q7 = *(const uint2*)&xs2b[s7 * 8 + l * 2];
            acc4(a0, q0); acc4(a1, q1); acc4(a2, q2); acc4(a3, q3);
            acc4(a0, q4); acc4(a1, q5); acc4(a2, q6); acc4(a3, q7);
        }
        for (; i < num; ++i) {
            uint2 q = *(const uint2*)&xs2b[cp[i] * 8 + l * 2];
            acc4(a0, q);
        }
        float ax = (a0.x + a1.x) + (a2.x + a3.x);
        float ay = (a0.y + a1.y) + (a2.y + a3.y);
        float az = (a0.z + a1.z) + (a2.z + a3.z);
        float aw = (a0.w + a1.w) + (a2.w + a3.w);
        float dv = dis[v];
        int g = batch[v];
        atomicAdd(&psum[g * C2 + l * 4 + 0], ax * dv);
        atomicAdd(&psum[g * C2 + l * 4 + 1], ay * dv);
        atomicAdd(&psum[g * C2 + l * 4 + 2], az * dv);
        atomicAdd(&psum[g * C2 + l * 4 + 3], aw * dv);
        if (l == 0) atomicAdd(&cs[g], 1.0f);
    }
    __syncthreads();
    for (int i = t; i < NG * C2; i += 256)
        if (psum[i] != 0.f) atomicAdd(&pool[i], psum[i]);
    if (t < NG && cs[t] != 0.f) atomicAdd(&cntf[t], cs[t]);
}

// ---------------- final: out[g] = (pool/cnt + b2) @ lw + lb -----------------
__global__ void k_final(const float* __restrict__ pool, const float* __restrict__ cntf,
                        const float* __restrict__ b2,
                        const float* __restrict__ lw, const float* __restrict__ lb,
                        float* __restrict__ out)
{
    int g = threadIdx.x;
    if (g < NG) {
        float c = fmaxf(cntf[g], 1.0f);
        float inv = 1.0f / c;
        float s = lb[0];
        #pragma unroll
        for (int k = 0; k < C2; ++k) {
            s = fmaf(b2[k], lw[k], s);                    // bias fold
            s = fmaf(pool[g * C2 + k] * inv, lw[k], s);
        }
        out[g] = s;
    }
}

extern "C" void kernel_launch(void* const* d_in, const int* in_sizes, int n_in,
                              void* d_out, int out_size, void* d_ws, size_t ws_size,
                              hipStream_t stream) {
    const float* x     = (const float*)d_in[0];
    const int*   ei    = (const int*)d_in[1];
    const int*   batch = (const int*)d_in[2];
    const float* W1    = (const float*)d_in[3];
    const float* b1    = (const float*)d_in[4];
    const float* W2    = (const float*)d_in[5];
    const float* b2    = (const float*)d_in[6];
    const float* lw    = (const float*)d_in[7];
    const float* lb    = (const float*)d_in[8];
    float* out = (float*)d_out;

    float*    wsf = (float*)d_ws;
    int*      wsi = (int*)d_ws;
    unsigned* wsu = (unsigned*)d_ws;

    int*      bcnt     = wsi + OFF_BCNT;
    int*      bstart   = wsi + OFF_BST;
    int*      runstart = wsi + OFF_RUN;
    int*      rowstart = wsi + OFF_ROW;
    float*    dis      = wsf + OFF_DIS;
    float*    pool     = wsf + OFF_POOL;
    float*    cntf     = wsf + OFF_CNTF;
    unsigned* edgebuf  = wsu + OFF_EDG;
    unsigned* xs1h0    = wsu + OFF_XS1H0;  // aliases edgebuf (dead after fillfused)
    unsigned* xs1h1    = wsu + OFF_XS1H1;
    float*    h1a      = wsf + OFF_H1A;
    unsigned* xs2b     = wsu + OFF_XS2B;
    int*      colidx   = wsi + OFF_COL;

    const int* S = ei;            // edge_index[0] (src)
    const int* D = ei + NE;       // edge_index[1] (dst)

    hipMemsetAsync(bcnt, 0, 1024 * sizeof(int), stream);
    hipMemsetAsync(pool, 0, (NG * C2 + NG) * sizeof(float), stream);

    k_part       <<<NW, 256, 0, stream>>>(S, D, edgebuf, runstart, bcnt);
    k_bscan      <<<1, 256, 0, stream>>>(bcnt, bstart, rowstart);
    k_fillfused  <<<NBKT, 256, 0, stream>>>(edgebuf, runstart, bstart, rowstart, dis, colidx);
    k_gemm1      <<<(NN + 127) / 128, 256, 0, stream>>>(x, W1, dis, xs1h0, xs1h1);
    k_gather1h<0><<<(NN + 63) / 64, 256, 0, stream>>>(xs1h0, colidx, rowstart, dis, b1, h1a, W2, xs2b);
    k_gather1h<1><<<(NN + 63) / 64, 256, 0, stream>>>(xs1h1, colidx, rowstart, dis, b1, h1a, W2, xs2b);
    k_gather2    <<<(NN + 63) / 64, 256, 0, stream>>>(xs2b, colidx, rowstart, dis, batch, pool, cntf);
    k_final      <<<1, 64, 0, stream>>>(pool, cntf, b2, lw, lb, out);
}